// Round 6
// baseline (104.372 us; speedup 1.0000x reference)
//
#include <hip/hip_runtime.h>
#include <stdint.h>

#define BATCH 32
#define CINX 128
#define FOUT 256
#define NCLS 10
#define NSTEP36 36   // 9 taps x 4 c-quarters of 32

typedef __bf16 bf16x8 __attribute__((ext_vector_type(8)));
typedef float f32x4 __attribute__((ext_vector_type(4)));

#define WT_SLAB 32768                                  // bf16 per (cls,tap)
#define WT_BYTES ((size_t)NCLS * 9 * WT_SLAB * 2)      // 5,898,240
#define Z_BYTES 4096
#define X16_BYTES ((size_t)BATCH * 4096 * CINX * 2)    // 33,554,432
#define WS_NEED (WT_BYTES + Z_BYTES + X16_BYTES)

#define BAR() __builtin_amdgcn_s_barrier()
#define SCHEDBAR() __builtin_amdgcn_sched_barrier(0)
#define LGKM0() asm volatile("s_waitcnt lgkmcnt(0)" ::: "memory")
#define VMW3() asm volatile("s_waitcnt vmcnt(3)" ::: "memory")
#define VMW0() asm volatile("s_waitcnt vmcnt(0)" ::: "memory")

__device__ __forceinline__ void gl16(const __bf16* g, __bf16* l) {
    __builtin_amdgcn_global_load_lds(
        (const __attribute__((address_space(1))) void*)g,
        (__attribute__((address_space(3))) void*)l, 16, 0, 0);
}

// ---------------------------------------------------------------------------
// prep_all: fused weight transpose+convert and x convert (one launch).
// blocks 0..89: kernel [cls][tap][c][f] f32 -> wt [slab][c32:4][f:256][slot:4]
//   bf16, pre-swizzled: slot holds c-chunk cu = slot ^ ((f>>1)&3).
// blocks 90.. : x f32 -> bf16 flat; block 90 also zeroes the pad slab.
// ---------------------------------------------------------------------------
__global__ __launch_bounds__(256) void prep_all(const float* __restrict__ kin,
                                                __bf16* __restrict__ wt,
                                                const float* __restrict__ x,
                                                __bf16* __restrict__ x16,
                                                __bf16* __restrict__ zbuf) {
    if (blockIdx.x < NCLS * 9) {
        __shared__ __bf16 tile[128 * 260];
        const int slab = blockIdx.x;
        const float* src = kin + (size_t)slab * (CINX * FOUT);
        __bf16* dst = wt + (size_t)slab * WT_SLAB;
        const int t = threadIdx.x;
#pragma unroll
        for (int i = 0; i < 32; ++i) {
            int e4 = t + i * 256;
            int c = e4 >> 6, f4 = e4 & 63;
            f32x4 v = *(const f32x4*)(src + (size_t)e4 * 4);
            __bf16* p = &tile[c * 260 + f4 * 4];
            p[0] = (__bf16)v[0]; p[1] = (__bf16)v[1];
            p[2] = (__bf16)v[2]; p[3] = (__bf16)v[3];
        }
        __syncthreads();
#pragma unroll
        for (int i = 0; i < 16; ++i) {
            int g = t + i * 256;          // 16B unit within slab
            int c32 = g >> 10;            // 32-c quarter
            int u = g & 1023;
            int f = u >> 2, slot = u & 3;
            int cu = slot ^ ((f >> 1) & 3);
            int c0 = c32 * 32 + cu * 8;
            bf16x8 o;
#pragma unroll
            for (int j = 0; j < 8; ++j) o[j] = tile[(c0 + j) * 260 + f];
            *(bf16x8*)(dst + (size_t)g * 8) = o;
        }
    } else {
        const int bx = blockIdx.x - NCLS * 9;
        const size_t u = (size_t)bx * 256 + threadIdx.x;  // 8-elem unit
        f32x4 a = *(const f32x4*)(x + u * 8);
        f32x4 c = *(const f32x4*)(x + u * 8 + 4);
        bf16x8 o;
#pragma unroll
        for (int j = 0; j < 4; ++j) { o[j] = (__bf16)a[j]; o[4 + j] = (__bf16)c[j]; }
        *(bf16x8*)(x16 + u * 8) = o;
        if (bx == 0 && threadIdx.x < 128) {
            bf16x8 z;
#pragma unroll
            for (int j = 0; j < 8; ++j) z[j] = (__bf16)0.f;
            *(bf16x8*)(zbuf + (size_t)threadIdx.x * 8) = z;
        }
    }
}

// ---------------------------------------------------------------------------
// conv_hi: 256px x 128f tile, BK=32, 36 K-steps, 8 waves (4M x 2N), per-wave
// 64x64 out (acc=64 VGPR). LDS double-buffered 48 KB -> 2 blocks/CU, 4
// waves/SIMD from INDEPENDENT blocks (desynced barriers -> one block's MFMA
// hides the other's stalls). Counted vmcnt(3), 2-step staging depth, raw
// barrier pairs, compile-time buffer parity (K-loop unrolled x2).
// ---------------------------------------------------------------------------
__global__ __launch_bounds__(512, 4) void conv_hi(
    const __bf16* __restrict__ xg16, const int* __restrict__ cls_g,
    const __bf16* __restrict__ wt, const float* __restrict__ bias,
    const __bf16* __restrict__ zbuf, float* __restrict__ out) {
    __shared__ __align__(16) __bf16 ldsA[2][256 * 32];  // 32 KB
    __shared__ __align__(16) __bf16 ldsB[2][128 * 32];  // 16 KB

    const int bid0 = blockIdx.x;
    const int swz  = (bid0 & 7) * 128 + (bid0 >> 3);  // 1024 blocks, bijective
    const int b    = swz >> 5;          // sample
    const int pt   = (swz >> 1) & 15;   // 4-row pixel tile
    const int ft   = swz & 1;           // 128-f half
    const int cls  = cls_g[b];
    const int y0   = pt << 2;

    const int tid  = threadIdx.x;
    const int lane = tid & 63;
    const int wid  = tid >> 6;
    const int wm   = wid >> 1;   // 0..3
    const int wn   = wid & 1;    // 0..1
    const int l15  = lane & 15;
    const int l4   = lane >> 4;

    const __bf16* xb   = xg16 + (size_t)b * 4096 * CINX;
    const __bf16* wcls = wt + (size_t)cls * 9 * WT_SLAB;

    // ---- loop-invariant A-staging coords (i=0,1 -> unit u = i*512+tid) ----
    int pyA[2], gxA[2], cuoffA[2];
#pragma unroll
    for (int i = 0; i < 2; ++i) {
        int u = i * 512 + tid;
        int px = u >> 2, slot = u & 3;
        pyA[i] = px >> 6;
        gxA[i] = px & 63;
        cuoffA[i] = (slot ^ ((px >> 1) & 3)) * 8;
    }
    // ---- loop-invariant fragment-read units ----
    const int swq = (l15 >> 1) & 3;
    int unA[4], unB[4];
#pragma unroll
    for (int mt = 0; mt < 4; ++mt)
        unA[mt] = (wm * 64 + mt * 16 + l15) * 4 + (l4 ^ swq);
#pragma unroll
    for (int nt = 0; nt < 4; ++nt)
        unB[nt] = (wn * 64 + nt * 16 + l15) * 4 + (l4 ^ swq);

    f32x4 acc[4][4];
#pragma unroll
    for (int i = 0; i < 4; ++i)
#pragma unroll
        for (int j = 0; j < 4; ++j)
#pragma unroll
            for (int r = 0; r < 4; ++r) acc[i][j][r] = 0.f;

    // stage one 32-c K-step (3 gload_lds/thread: 2 A + 1 B)
    auto stage = [&](int s2, int buf) {
        const int tap = s2 >> 2, c32 = s2 & 3;
        const int dy = tap / 3 - 1, dx = tap % 3 - 1;
        const int choff = c32 * 32;
#pragma unroll
        for (int i = 0; i < 2; ++i) {
            const int u = i * 512 + tid;
            const int gy = y0 + pyA[i] + dy;
            const int gx = gxA[i] + dx;
            const bool v = ((unsigned)gy < 64u) && ((unsigned)gx < 64u);
            const __bf16* src = v
                ? (xb + ((size_t)(gy * 64 + gx)) * CINX + choff + cuoffA[i])
                : (zbuf + (size_t)(u & 63) * 8);
            gl16(src, &ldsA[buf][(size_t)u * 8]);
        }
        const __bf16* wsrc = wcls + (size_t)tap * WT_SLAB +
                             (size_t)(c32 * 1024 + ft * 512 + tid) * 8;
        gl16(wsrc, &ldsB[buf][(size_t)tid * 8]);
    };

    bf16x8 afr[4], bfr[4];
    auto rdfrags = [&](int buf) {
#pragma unroll
        for (int mt = 0; mt < 4; ++mt)
            afr[mt] = *(const bf16x8*)&ldsA[buf][(size_t)unA[mt] * 8];
#pragma unroll
        for (int nt = 0; nt < 4; ++nt)
            bfr[nt] = *(const bf16x8*)&ldsB[buf][(size_t)unB[nt] * 8];
    };
    auto mm = [&]() {
        __builtin_amdgcn_s_setprio(1);
#pragma unroll
        for (int mt = 0; mt < 4; ++mt)
#pragma unroll
            for (int nt = 0; nt < 4; ++nt)
                acc[mt][nt] = __builtin_amdgcn_mfma_f32_16x16x32_bf16(
                    afr[mt], bfr[nt], acc[mt][nt], 0, 0, 0);
        __builtin_amdgcn_s_setprio(0);
    };

    // prologue: steps 0,1 in flight; land step 0; publish b0
    stage(0, 0);
    stage(1, 1);
    VMW3();
    BAR();

    // main loop, unrolled x2 for compile-time buffer parity
    for (int s = 0; s < NSTEP36 - 2; s += 2) {
#pragma unroll
        for (int half = 0; half < 2; ++half) {
            const int buf = half;          // compile-time after unroll
            rdfrags(buf);                  // 8 ds_read_b128
            LGKM0();                       // frags in regs (cross-wave WAR)
            SCHEDBAR();
            BAR();                         // all waves done reading buf
            stage(s + half + 2, buf);      // overwrite buf; 6 outstanding
            mm();                          // 16 MFMA; loads fly underneath
            VMW3();                        // land stage(s+half+1)
            BAR();                         // publish buf^1
        }
    }
    // peeled: s = 34 (buf 0), s = 35 (buf 1)
    rdfrags(0);
    LGKM0();
    SCHEDBAR();
    BAR();
    mm();
    VMW0();
    BAR();
    rdfrags(1);
    LGKM0();
    SCHEDBAR();
    mm();

    // ---- epilogue: bias + f32 store ----
    float bv[4];
#pragma unroll
    for (int nt = 0; nt < 4; ++nt)
        bv[nt] = bias[cls * FOUT + ft * 128 + wn * 64 + nt * 16 + l15];

    float* ob = out + ((size_t)b * 4096 + (size_t)pt * 256) * FOUT + ft * 128;
#pragma unroll
    for (int mt = 0; mt < 4; ++mt) {
#pragma unroll
        for (int r = 0; r < 4; ++r) {
            const int row = wm * 64 + mt * 16 + l4 * 4 + r;
            float* orow = ob + (size_t)row * FOUT;
#pragma unroll
            for (int nt = 0; nt < 4; ++nt)
                orow[wn * 64 + nt * 16 + l15] = acc[mt][nt][r] + bv[nt];
        }
    }
}

// ===========================================================================
// Fallback path (round-2 kernels) if ws_size < WS_NEED
// ===========================================================================
__global__ __launch_bounds__(256) void prep_w_fb(const float* __restrict__ kin,
                                                 __bf16* __restrict__ wt) {
    __shared__ __bf16 tile[128 * 260];
    const int slab = blockIdx.x;
    const float* src = kin + (size_t)slab * (CINX * FOUT);
    __bf16* dst = wt + (size_t)slab * (16 * 256 * 8);
    const int t = threadIdx.x;
#pragma unroll
    for (int i = 0; i < 32; ++i) {
        int e4 = t + i * 256;
        int c = e4 >> 6, f4 = e4 & 63;
        f32x4 v = *(const f32x4*)(src + (size_t)e4 * 4);
        __bf16* p = &tile[c * 260 + f4 * 4];
        p[0] = (__bf16)v[0]; p[1] = (__bf16)v[1];
        p[2] = (__bf16)v[2]; p[3] = (__bf16)v[3];
    }
    __syncthreads();
#pragma unroll
    for (int i = 0; i < 16; ++i) {
        int g = t + i * 256;
        int cu = g >> 8, f = g & 255;
        bf16x8 o;
#pragma unroll
        for (int j = 0; j < 8; ++j) o[j] = tile[(cu * 8 + j) * 260 + f];
        *(bf16x8*)(dst + (size_t)g * 8) = o;
    }
}

__global__ __launch_bounds__(512, 2) void conv_fb(
    const float* __restrict__ xg, const int* __restrict__ cls_g,
    const __bf16* __restrict__ wt, const float* __restrict__ bias,
    float* __restrict__ out) {
    __shared__ __align__(16) __bf16 ldsA[2][8 * 256 * 8];
    __shared__ __align__(16) __bf16 ldsB[2][8 * 256 * 8];
    const int bid0 = blockIdx.x;
    const int swz = (bid0 & 7) * 64 + (bid0 >> 3);
    const int b = swz >> 4, pt = swz & 15;
    const int cls = cls_g[b];
    const int y0 = pt << 2;
    const int tid = threadIdx.x, lane = tid & 63, wid = tid >> 6;
    const int wm = wid >> 2, wn = wid & 3, l15 = lane & 15, l4 = lane >> 4;
    const float* xb = xg + (size_t)b * 4096 * CINX;
    const __bf16* wcls = wt + (size_t)cls * 9 * (16 * 256 * 8);
    const int tpx = tid >> 1, tch = (tid & 1) * 32;
    const int py = tpx >> 6, px_ = tpx & 63;
    f32x4 acc[8][4];
#pragma unroll
    for (int i = 0; i < 8; ++i)
#pragma unroll
        for (int j = 0; j < 4; ++j)
#pragma unroll
            for (int r = 0; r < 4; ++r) acc[i][j][r] = 0.f;
    f32x4 va[8];
    auto issueB = [&](int s, int buf) {
        const int tap = s >> 1, chalf = (s & 1) << 6;
        const __bf16* wsrc = wcls + (size_t)tap * (16 * 256 * 8) + chalf * 256;
#pragma unroll
        for (int i = 0; i < 4; ++i) {
            const int u = i * 512 + tid;
            gl16(wsrc + (size_t)u * 8, &ldsB[buf][(size_t)u * 8]);
        }
    };
    auto issueA = [&](int s) {
        const int tap = s >> 1, chalf = (s & 1) << 6;
        const int dy = tap / 3 - 1, dx = tap % 3 - 1;
        const int gy = y0 + py + dy, gx = px_ + dx;
        const bool valid = ((unsigned)gy < 64u) && ((unsigned)gx < 64u);
        const float* src = xb + ((size_t)(gy * 64 + gx)) * CINX + chalf + tch;
        if (valid) {
#pragma unroll
            for (int j2 = 0; j2 < 8; ++j2) va[j2] = *(const f32x4*)(src + j2 * 4);
        } else {
#pragma unroll
            for (int j2 = 0; j2 < 8; ++j2)
#pragma unroll
                for (int q = 0; q < 4; ++q) va[j2][q] = 0.f;
        }
    };
    auto writeA = [&](int buf) {
#pragma unroll
        for (int j = 0; j < 4; ++j) {
            bf16x8 pk;
#pragma unroll
            for (int q = 0; q < 4; ++q) {
                pk[q] = (__bf16)va[2 * j][q];
                pk[4 + q] = (__bf16)va[2 * j + 1][q];
            }
            const int u = ((tid & 1) * 4 + j) * 256 + tpx;
            *(bf16x8*)(&ldsA[buf][(size_t)u * 8]) = pk;
        }
    };
    auto compute = [&](int buf) {
#pragma unroll
        for (int kk = 0; kk < 2; ++kk) {
            const int cu = kk * 4 + l4;
            bf16x8 afr[8], bfr[4];
#pragma unroll
            for (int mt = 0; mt < 8; ++mt)
                afr[mt] = *(const bf16x8*)(
                    &ldsA[buf][(size_t)(cu * 256 + wm * 128 + mt * 16 + l15) * 8]);
#pragma unroll
            for (int nt = 0; nt < 4; ++nt)
                bfr[nt] = *(const bf16x8*)(
                    &ldsB[buf][(size_t)(cu * 256 + wn * 64 + nt * 16 + l15) * 8]);
#pragma unroll
            for (int mt = 0; mt < 8; ++mt)
#pragma unroll
                for (int nt = 0; nt < 4; ++nt)
                    acc[mt][nt] = __builtin_amdgcn_mfma_f32_16x16x32_bf16(
                        afr[mt], bfr[nt], acc[mt][nt], 0, 0, 0);
        }
    };
    issueB(0, 0);
    issueA(0);
    writeA(0);
    __syncthreads();
    int cur = 0;
    for (int s = 0; s < 17; ++s) {
        issueB(s + 1, cur ^ 1);
        issueA(s + 1);
        compute(cur);
        writeA(cur ^ 1);
        __syncthreads();
        cur ^= 1;
    }
    compute(cur);
    float bv[4];
#pragma unroll
    for (int nt = 0; nt < 4; ++nt)
        bv[nt] = bias[cls * FOUT + wn * 64 + nt * 16 + l15];
    float* ob = out + ((size_t)b * 4096 + (size_t)pt * 256) * FOUT;
#pragma unroll
    for (int mt = 0; mt < 8; ++mt) {
#pragma unroll
        for (int r = 0; r < 4; ++r) {
            const int row = wm * 128 + mt * 16 + l4 * 4 + r;
            float* orow = ob + (size_t)row * FOUT;
#pragma unroll
            for (int nt = 0; nt < 4; ++nt)
                orow[wn * 64 + nt * 16 + l15] = acc[mt][nt][r] + bv[nt];
        }
    }
}

extern "C" void kernel_launch(void* const* d_in, const int* in_sizes, int n_in,
                              void* d_out, int out_size, void* d_ws, size_t ws_size,
                              hipStream_t stream) {
    const float* x       = (const float*)d_in[0];
    const int*   classes = (const int*)d_in[1];
    const float* kin     = (const float*)d_in[2];
    const float* bias    = (const float*)d_in[3];
    float* out = (float*)d_out;

    char* ws = (char*)d_ws;
    __bf16* wt   = (__bf16*)ws;
    __bf16* zbuf = (__bf16*)(ws + WT_BYTES);
    __bf16* x16  = (__bf16*)(ws + WT_BYTES + Z_BYTES);

    if (ws_size >= WS_NEED) {
        prep_all<<<dim3(NCLS * 9 + 8192), dim3(256), 0, stream>>>(kin, wt, x,
                                                                  x16, zbuf);
        conv_hi<<<dim3(1024), dim3(512), 0, stream>>>(x16, classes, wt, bias,
                                                      zbuf, out);
    } else {
        prep_w_fb<<<dim3(NCLS * 9), dim3(256), 0, stream>>>(kin, wt);
        conv_fb<<<dim3(512), dim3(512), 0, stream>>>(x, classes, wt, bias, out);
    }
}